// Round 1
// baseline (13058.791 us; speedup 1.0000x reference)
//
#include <hip/hip_runtime.h>
#include <math.h>

// ---------------------------------------------------------------------------
// LSTM RNN, B=128, T=1024, H=256, IN=OUT=1, predict=8  (all fp32)
//
// Architecture: "stationary Uh" persistent kernel.
//   - 256 workgroups = 32 batch-groups (R) x 8 column-groups (C), 1 WG per CU.
//   - Each WG keeps its Uh slice (256 k x 128 gate-cols = 128 KiB) in LDS for
//     the whole run; only h (512 B/WG/step) moves through global memory.
//   - Per-step sync: per-producer monotonic flags, agent-scope atomics,
//     double-buffered h. Batch groups are fully independent (no grid barrier).
// ---------------------------------------------------------------------------

#define NTH   256
#define Bn    128
#define Tn    1024
#define Hn    256
#define G4    1024          // 4*H
#define TPn   1032          // T + predict
#define Cc    8             // column (hidden-slice) splits
#define NB    4             // batch rows per WG  (B / 32)
#define Mm    32            // hidden cols per gate per WG (H / Cc)
#define COLS  128           // 4 gates * Mm
#define UH_LD 260           // 256 + 4 pad -> conflict-free b128 reads
#define FLAG_STRIDE 32      // ints; one flag per 128B to avoid line contention

// LDS layout (float offsets)
#define OFF_UH   0
#define OFF_H    (COLS*UH_LD)            // 33280  : h_s[k][NB]
#define OFF_RED  (OFF_H + Hn*NB)         // 34304  : red[2][COLS][NB]
#define OFF_WX   (OFF_RED + 2*COLS*NB)   // 35328
#define OFF_BU   (OFF_WX + COLS)         // 35456
#define OFF_WOUT (OFF_BU + COLS)         // 35584
#define OFF_OS   (OFF_WOUT + Hn)         // 35840  : o_s[NB] (+pad)
#define OFF_SEQ  (OFF_OS + 16)           // 35856  : seq_s[NB][T]
#define SMEM_FLOATS (OFF_SEQ + NB*Tn)    // 39952
#define SMEM_BYTES  (SMEM_FLOATS*4)      // 159808 B  (< 160 KiB/CU)

__global__ void init_flags(int* flags) {
  int i = threadIdx.x + blockIdx.x * blockDim.x;
  for (; i < 256 * FLAG_STRIDE; i += blockDim.x * gridDim.x) flags[i] = 0;
}

__global__ __launch_bounds__(NTH) void lstm_persistent(
    const float* __restrict__ seq, const float* __restrict__ Wx,
    const float* __restrict__ Uh,  const float* __restrict__ bu,
    const float* __restrict__ Wout,const float* __restrict__ bout,
    float* __restrict__ out, int* __restrict__ flags, float* __restrict__ hbuf)
{
  extern __shared__ float sm[];
  const int tid = threadIdx.x;
  const int bid = blockIdx.x;
  const int cw  = bid & (Cc - 1);   // column group 0..7
  const int rw  = bid >> 3;         // batch group 0..31
  const int b0  = rw * NB;

  float* Uh_s   = sm + OFF_UH;
  float* h_s    = sm + OFF_H;
  float* red    = sm + OFF_RED;
  float* Wx_s   = sm + OFF_WX;
  float* bu_s   = sm + OFF_BU;
  float* Wout_s = sm + OFF_WOUT;
  float* o_s    = sm + OFF_OS;
  float* seq_s  = sm + OFF_SEQ;

  // ---- one-time staging -------------------------------------------------
  // Uh slice, transposed to [local col j][k];  j = gate*32 + m
  for (int idx = tid; idx < COLS * Hn; idx += NTH) {
    int j = idx & (COLS - 1);
    int k = idx >> 7;
    int g = j >> 5, m = j & 31;
    int gc = g * Hn + cw * Mm + m;              // global gate column
    Uh_s[j * UH_LD + k] = Uh[k * G4 + gc];
  }
  for (int j = tid; j < COLS; j += NTH) {
    int g = j >> 5, m = j & 31;
    int gc = g * Hn + cw * Mm + m;
    Wx_s[j] = Wx[gc];
    bu_s[j] = bu[gc];
  }
  for (int k = tid; k < Hn; k += NTH) Wout_s[k] = Wout[k];
  for (int idx = tid; idx < NB * Tn; idx += NTH) {
    int b = idx >> 10, t = idx & (Tn - 1);
    seq_s[idx] = seq[(b0 + b) * Tn + t];
  }
  const float bout_v = bout[0];
  float c_reg = 0.f;                 // cell state: thread tid<128 owns (b,m)
  __syncthreads();

  float* hb0 = hbuf;                 // double-buffered h, [B][H] each
  float* hb1 = hbuf + Bn * Hn;

  const int gb = tid >> 6;           // wave id == batch row for gather/o
  const int gl = tid & 63;

  for (int t = 0; t < TPn; ++t) {
    // ---- obtain h_t into h_s[k][b] -------------------------------------
    if (t == 0) {
      for (int i = tid; i < Hn * NB; i += NTH) h_s[i] = 0.f;
      __syncthreads();
    } else {
      if (tid < Cc) {
        while (__hip_atomic_load(&flags[(rw * Cc + tid) * FLAG_STRIDE],
                                 __ATOMIC_ACQUIRE, __HIP_MEMORY_SCOPE_AGENT) < t) {}
      }
      __syncthreads();
      const float* src = (t & 1) ? hb1 : hb0;
      #pragma unroll
      for (int i = 0; i < 4; ++i) {
        int k = gl + 64 * i;
        float v = __hip_atomic_load(&src[(b0 + gb) * Hn + k],
                                    __ATOMIC_RELAXED, __HIP_MEMORY_SCOPE_AGENT);
        h_s[k * NB + gb] = v;
      }
      __syncthreads();
    }

    // ---- o_{t-1} = Wout . h_t + bout (outputs for cw==0; feedback for all
    //      WGs during the predict phase) --------------------------------
    const bool need_o = (cw == 0) || (t >= Tn);
    if (need_o) {
      float p = 0.f;
      #pragma unroll
      for (int i = 0; i < 4; ++i) {
        int k = gl + 64 * i;
        p += h_s[k * NB + gb] * Wout_s[k];
      }
      for (int off = 32; off; off >>= 1) p += __shfl_down(p, off, 64);
      if (gl == 0) o_s[gb] = p + bout_v;
      __syncthreads();
      if (cw == 0 && t >= 1 && tid < NB) out[(b0 + tid) * TPn + (t - 1)] = o_s[tid];
    }

    // ---- matvec partials: red[kh][j][b] = sum_{k in half} Uh[k,j]*h[b,k] --
    {
      const int j  = tid & (COLS - 1);
      const int kh = tid >> 7;
      const float* uh = Uh_s + j * UH_LD + kh * 128;
      const float* hr = h_s + kh * 128 * NB;
      float a0 = 0.f, a1 = 0.f, a2 = 0.f, a3 = 0.f;
      #pragma unroll
      for (int q = 0; q < 32; ++q) {
        float4 u  = *(const float4*)(uh + 4 * q);
        float4 x0 = *(const float4*)(hr + 16 * q);       // h[k  ][0..3]
        float4 x1 = *(const float4*)(hr + 16 * q + 4);   // broadcast reads
        float4 x2 = *(const float4*)(hr + 16 * q + 8);
        float4 x3 = *(const float4*)(hr + 16 * q + 12);
        a0 += u.x * x0.x + u.y * x1.x + u.z * x2.x + u.w * x3.x;
        a1 += u.x * x0.y + u.y * x1.y + u.z * x2.y + u.w * x3.y;
        a2 += u.x * x0.z + u.y * x1.z + u.z * x2.z + u.w * x3.z;
        a3 += u.x * x0.w + u.y * x1.w + u.z * x2.w + u.w * x3.w;
      }
      *(float4*)(red + (kh * COLS + (tid & (COLS - 1))) * NB) = make_float4(a0, a1, a2, a3);
    }
    __syncthreads();

    // ---- gate nonlinearities + state update (threads 0..127: (b,m)) -----
    if (tid < 128) {
      const int b = tid >> 5, m = tid & 31;
      const float xp = (t < Tn) ? seq_s[b * Tn + t] : o_s[b];
      float gv[4];
      #pragma unroll
      for (int g = 0; g < 4; ++g) {
        int j = g * Mm + m;
        gv[g] = red[j * NB + b] + red[(COLS + j) * NB + b]
              + bu_s[j] + xp * Wx_s[j];
      }
      float it  = 1.f / (1.f + expf(-gv[0]));
      float ft  = 1.f / (1.f + expf(-gv[1]));
      float ot  = 1.f / (1.f + expf(-gv[2]));
      float cin = tanhf(gv[3]);
      c_reg = ft * c_reg + it * cin;
      float hn = ot * tanhf(c_reg);
      float* dst = ((t + 1) & 1) ? hb1 : hb0;
      __hip_atomic_store(&dst[(b0 + b) * Hn + cw * Mm + m], hn,
                         __ATOMIC_RELAXED, __HIP_MEMORY_SCOPE_AGENT);
    }
    __syncthreads();   // compiler drains vmcnt(0) before s_barrier
    if (tid == 0) {
      __threadfence();
      __hip_atomic_store(&flags[(rw * Cc + cw) * FLAG_STRIDE], t + 1,
                         __ATOMIC_RELEASE, __HIP_MEMORY_SCOPE_AGENT);
    }
  }

  // ---- final output column (needs h_{T+P}) ------------------------------
  if (cw == 0) {
    if (tid < Cc) {
      while (__hip_atomic_load(&flags[(rw * Cc + tid) * FLAG_STRIDE],
                               __ATOMIC_ACQUIRE, __HIP_MEMORY_SCOPE_AGENT) < TPn) {}
    }
    __syncthreads();
    const float* src = (TPn & 1) ? hb1 : hb0;
    #pragma unroll
    for (int i = 0; i < 4; ++i) {
      int k = gl + 64 * i;
      float v = __hip_atomic_load(&src[(b0 + gb) * Hn + k],
                                  __ATOMIC_RELAXED, __HIP_MEMORY_SCOPE_AGENT);
      h_s[k * NB + gb] = v;
    }
    __syncthreads();
    float p = 0.f;
    #pragma unroll
    for (int i = 0; i < 4; ++i) {
      int k = gl + 64 * i;
      p += h_s[k * NB + gb] * Wout_s[k];
    }
    for (int off = 32; off; off >>= 1) p += __shfl_down(p, off, 64);
    if (gl == 0) out[(b0 + gb) * TPn + (TPn - 1)] = p + bout_v;
  }
}

extern "C" void kernel_launch(void* const* d_in, const int* in_sizes, int n_in,
                              void* d_out, int out_size, void* d_ws, size_t ws_size,
                              hipStream_t stream) {
  const float* seq  = (const float*)d_in[0];
  const float* Wx   = (const float*)d_in[1];
  const float* Uh   = (const float*)d_in[2];
  const float* bu   = (const float*)d_in[3];
  const float* Wout = (const float*)d_in[4];
  const float* bout = (const float*)d_in[5];
  // d_in[6] = predict (fixed at 8; baked into TPn)
  float* out  = (float*)d_out;
  int*   flags = (int*)d_ws;                          // 32 KiB
  float* hbuf  = (float*)((char*)d_ws + 64 * 1024);   // 256 KiB (2 x [B][H])

  hipFuncSetAttribute((const void*)lstm_persistent,
                      hipFuncAttributeMaxDynamicSharedMemorySize, SMEM_BYTES);

  init_flags<<<8, 256, 0, stream>>>(flags);
  lstm_persistent<<<256, NTH, SMEM_BYTES, stream>>>(seq, Wx, Uh, bu, Wout,
                                                    bout, out, flags, hbuf);
}

// Round 4
// 7474.236 us; speedup vs baseline: 1.7472x; 1.7472x over previous
//
#include <hip/hip_runtime.h>
#include <math.h>

// ---------------------------------------------------------------------------
// LSTM RNN, B=128, T=1024, H=256, IN=OUT=1, predict=8  (all fp32)
//
// "Stationary Uh" persistent kernel:
//   - 256 WGs = 32 batch-groups x 8 column-groups, 1 WG/CU (160KB LDS forces
//     1/CU, so co-residency of all 256 is guaranteed -> flag sync safe).
//   - Uh slice (128 KiB) lives in LDS all 1032 steps; only h (512 B/WG/step)
//     moves through global (agent-scope, coherence-point) memory.
//   - R2 changes vs R1: (a) RELAXED poll + single trailing ACQUIRE (R1 did an
//     agent-scope acquire -> cache invalidate EVERY poll iteration, nuking
//     the XCD L2 continuously); (b) removed per-step __threadfence() (device
//     fence -> L2 writeback each step; redundant w/ RELEASE flag store);
//     (c) Uh LDS layout [kblk][j][4] -> conflict-free b128 reads (R1's
//     stride-260 was 8-way conflicted).
//   - Rounds 2 & 3 were infra failures (GPU acquisition timeout); this is an
//     unchanged resubmit to get the A/B measurement for the R2 changes.
// ---------------------------------------------------------------------------

#define NTH   256
#define Bn    128
#define Tn    1024
#define Hn    256
#define G4    1024          // 4*H
#define TPn   1032          // T + predict
#define Cc    8             // column (hidden-slice) splits
#define NB    4             // batch rows per WG  (B / 32)
#define Mm    32            // hidden cols per gate per WG (H / Cc)
#define COLS  128           // 4 gates * Mm
#define FLAG_STRIDE 32      // ints; one flag per 128B line

// LDS layout (float offsets)
#define OFF_UH   0                       // Uh_s[kblk=64][j=128][4] = 32768
#define OFF_H    (64*COLS*4)             // 32768 : h_s[k][NB]
#define OFF_RED  (OFF_H + Hn*NB)         // 33792 : red[2][COLS][NB]
#define OFF_WX   (OFF_RED + 2*COLS*NB)   // 34816
#define OFF_BU   (OFF_WX + COLS)         // 34944
#define OFF_WOUT (OFF_BU + COLS)         // 35072
#define OFF_OS   (OFF_WOUT + Hn)         // 35328 : o_s[NB] (+pad)
#define OFF_SEQ  (OFF_OS + 16)           // 35344 : seq_s[NB][T]
#define SMEM_FLOATS (OFF_SEQ + NB*Tn)    // 39440
#define SMEM_BYTES  (SMEM_FLOATS*4)      // 157760 B (< 160 KiB/CU)

__global__ void init_flags(int* flags) {
  int i = threadIdx.x + blockIdx.x * blockDim.x;
  for (; i < 256 * FLAG_STRIDE; i += blockDim.x * gridDim.x) flags[i] = 0;
}

__global__ __launch_bounds__(NTH) void lstm_persistent(
    const float* __restrict__ seq, const float* __restrict__ Wx,
    const float* __restrict__ Uh,  const float* __restrict__ bu,
    const float* __restrict__ Wout,const float* __restrict__ bout,
    float* __restrict__ out, int* __restrict__ flags, float* __restrict__ hbuf)
{
  extern __shared__ float sm[];
  const int tid = threadIdx.x;
  const int bid = blockIdx.x;
  const int cw  = bid & (Cc - 1);   // column group 0..7
  const int rw  = bid >> 3;         // batch group 0..31
  const int b0  = rw * NB;

  float* Uh_s   = sm + OFF_UH;
  float* h_s    = sm + OFF_H;
  float* red    = sm + OFF_RED;
  float* Wx_s   = sm + OFF_WX;
  float* bu_s   = sm + OFF_BU;
  float* Wout_s = sm + OFF_WOUT;
  float* o_s    = sm + OFF_OS;
  float* seq_s  = sm + OFF_SEQ;

  // ---- one-time staging -------------------------------------------------
  // Uh slice, layout [k>>2][j][k&3]: thread j's float4 read over k is the
  // canonical consecutive-lane/consecutive-float4 pattern (conflict-free).
  for (int idx = tid; idx < COLS * Hn; idx += NTH) {
    int j = idx & (COLS - 1);
    int k = idx >> 7;
    int g = j >> 5, m = j & 31;
    int gc = g * Hn + cw * Mm + m;              // global gate column
    Uh_s[(k >> 2) * (COLS * 4) + j * 4 + (k & 3)] = Uh[k * G4 + gc];
  }
  for (int j = tid; j < COLS; j += NTH) {
    int g = j >> 5, m = j & 31;
    int gc = g * Hn + cw * Mm + m;
    Wx_s[j] = Wx[gc];
    bu_s[j] = bu[gc];
  }
  for (int k = tid; k < Hn; k += NTH) Wout_s[k] = Wout[k];
  for (int idx = tid; idx < NB * Tn; idx += NTH) {
    int b = idx >> 10, t = idx & (Tn - 1);
    seq_s[idx] = seq[(b0 + b) * Tn + t];
  }
  const float bout_v = bout[0];
  float c_reg = 0.f;                 // cell state: thread tid<128 owns (b,m)
  __syncthreads();

  float* hb0 = hbuf;                 // double-buffered h, [B][H] each
  float* hb1 = hbuf + Bn * Hn;

  const int gb = tid >> 6;           // wave id == batch row for gather/o
  const int gl = tid & 63;

  for (int t = 0; t < TPn; ++t) {
    // ---- obtain h_t into h_s[k][b] -------------------------------------
    if (t == 0) {
      for (int i = tid; i < Hn * NB; i += NTH) h_s[i] = 0.f;
      __syncthreads();
    } else {
      if (tid < Cc) {
        // RELAXED spin (no per-iteration cache inv), then ONE acquire load
        // (flag monotonic -> still >= t) to establish ordering.
        while (__hip_atomic_load(&flags[(rw * Cc + tid) * FLAG_STRIDE],
                                 __ATOMIC_RELAXED, __HIP_MEMORY_SCOPE_AGENT) < t) {}
        (void)__hip_atomic_load(&flags[(rw * Cc + tid) * FLAG_STRIDE],
                                __ATOMIC_ACQUIRE, __HIP_MEMORY_SCOPE_AGENT);
      }
      __syncthreads();
      const float* src = (t & 1) ? hb1 : hb0;
      #pragma unroll
      for (int i = 0; i < 4; ++i) {
        int k = gl + 64 * i;
        float v = __hip_atomic_load(&src[(b0 + gb) * Hn + k],
                                    __ATOMIC_RELAXED, __HIP_MEMORY_SCOPE_AGENT);
        h_s[k * NB + gb] = v;
      }
      __syncthreads();
    }

    // ---- o_{t-1} = Wout . h_t + bout (outputs for cw==0; feedback for all
    //      WGs during the predict phase) --------------------------------
    const bool need_o = (cw == 0) || (t >= Tn);
    if (need_o) {
      float p = 0.f;
      #pragma unroll
      for (int i = 0; i < 4; ++i) {
        int k = gl + 64 * i;
        p += h_s[k * NB + gb] * Wout_s[k];
      }
      for (int off = 32; off; off >>= 1) p += __shfl_down(p, off, 64);
      if (gl == 0) o_s[gb] = p + bout_v;
      __syncthreads();
      if (cw == 0 && t >= 1 && tid < NB) out[(b0 + tid) * TPn + (t - 1)] = o_s[tid];
    }

    // ---- matvec partials: red[kh][j][b] = sum_{k in half} Uh[k,j]*h[b,k] --
    {
      const int j  = tid & (COLS - 1);
      const int kh = tid >> 7;
      const float* uh = Uh_s + (kh * 32) * (COLS * 4) + j * 4;
      const float* hr = h_s + kh * 128 * NB;
      float a0 = 0.f, a1 = 0.f, a2 = 0.f, a3 = 0.f;
      #pragma unroll
      for (int q = 0; q < 32; ++q) {
        float4 u  = *(const float4*)(uh + q * (COLS * 4));   // (j, 4k..4k+3)
        float4 x0 = *(const float4*)(hr + 16 * q);           // h[k  ][0..3]
        float4 x1 = *(const float4*)(hr + 16 * q + 4);       // broadcast
        float4 x2 = *(const float4*)(hr + 16 * q + 8);
        float4 x3 = *(const float4*)(hr + 16 * q + 12);
        a0 += u.x * x0.x + u.y * x1.x + u.z * x2.x + u.w * x3.x;
        a1 += u.x * x0.y + u.y * x1.y + u.z * x2.y + u.w * x3.y;
        a2 += u.x * x0.z + u.y * x1.z + u.z * x2.z + u.w * x3.z;
        a3 += u.x * x0.w + u.y * x1.w + u.z * x2.w + u.w * x3.w;
      }
      *(float4*)(red + (kh * COLS + j) * NB) = make_float4(a0, a1, a2, a3);
    }
    __syncthreads();

    // ---- gate nonlinearities + state update (threads 0..127: (b,m)) -----
    if (tid < 128) {
      const int b = tid >> 5, m = tid & 31;
      const float xp = (t < Tn) ? seq_s[b * Tn + t] : o_s[b];
      float gv[4];
      #pragma unroll
      for (int g = 0; g < 4; ++g) {
        int j = g * Mm + m;
        gv[g] = red[j * NB + b] + red[(COLS + j) * NB + b]
              + bu_s[j] + xp * Wx_s[j];
      }
      float it  = 1.f / (1.f + expf(-gv[0]));
      float ft  = 1.f / (1.f + expf(-gv[1]));
      float ot  = 1.f / (1.f + expf(-gv[2]));
      float cin = tanhf(gv[3]);
      c_reg = ft * c_reg + it * cin;
      float hn = ot * tanhf(c_reg);
      float* dst = ((t + 1) & 1) ? hb1 : hb0;
      __hip_atomic_store(&dst[(b0 + b) * Hn + cw * Mm + m], hn,
                         __ATOMIC_RELAXED, __HIP_MEMORY_SCOPE_AGENT);
    }
    __syncthreads();   // every wave drains vmcnt(0) before s_barrier
    if (tid == 0) {
      // RELEASE orders the (already-drained) h stores before the flag.
      __hip_atomic_store(&flags[(rw * Cc + cw) * FLAG_STRIDE], t + 1,
                         __ATOMIC_RELEASE, __HIP_MEMORY_SCOPE_AGENT);
    }
  }

  // ---- final output column (needs h_{T+P}) ------------------------------
  if (cw == 0) {
    if (tid < Cc) {
      while (__hip_atomic_load(&flags[(rw * Cc + tid) * FLAG_STRIDE],
                               __ATOMIC_RELAXED, __HIP_MEMORY_SCOPE_AGENT) < TPn) {}
      (void)__hip_atomic_load(&flags[(rw * Cc + tid) * FLAG_STRIDE],
                              __ATOMIC_ACQUIRE, __HIP_MEMORY_SCOPE_AGENT);
    }
    __syncthreads();
    const float* src = (TPn & 1) ? hb1 : hb0;
    #pragma unroll
    for (int i = 0; i < 4; ++i) {
      int k = gl + 64 * i;
      float v = __hip_atomic_load(&src[(b0 + gb) * Hn + k],
                                  __ATOMIC_RELAXED, __HIP_MEMORY_SCOPE_AGENT);
      h_s[k * NB + gb] = v;
    }
    __syncthreads();
    float p = 0.f;
    #pragma unroll
    for (int i = 0; i < 4; ++i) {
      int k = gl + 64 * i;
      p += h_s[k * NB + gb] * Wout_s[k];
    }
    for (int off = 32; off; off >>= 1) p += __shfl_down(p, off, 64);
    if (gl == 0) out[(b0 + gb) * TPn + (TPn - 1)] = p + bout_v;
  }
}

extern "C" void kernel_launch(void* const* d_in, const int* in_sizes, int n_in,
                              void* d_out, int out_size, void* d_ws, size_t ws_size,
                              hipStream_t stream) {
  const float* seq  = (const float*)d_in[0];
  const float* Wx   = (const float*)d_in[1];
  const float* Uh   = (const float*)d_in[2];
  const float* bu   = (const float*)d_in[3];
  const float* Wout = (const float*)d_in[4];
  const float* bout = (const float*)d_in[5];
  // d_in[6] = predict (fixed at 8; baked into TPn)
  float* out  = (float*)d_out;
  int*   flags = (int*)d_ws;                          // 32 KiB
  float* hbuf  = (float*)((char*)d_ws + 64 * 1024);   // 256 KiB (2 x [B][H])

  hipFuncSetAttribute((const void*)lstm_persistent,
                      hipFuncAttributeMaxDynamicSharedMemorySize, SMEM_BYTES);

  init_flags<<<8, 256, 0, stream>>>(flags);
  lstm_persistent<<<256, NTH, SMEM_BYTES, stream>>>(seq, Wx, Uh, bu, Wout,
                                                    bout, out, flags, hbuf);
}